// Round 4
// baseline (285.414 us; speedup 1.0000x reference)
//
#include <hip/hip_runtime.h>

// Problem constants (from reference): B=32, CIN=64, COUT=64, H=W=128, 1x1 conv
#define CIN   64
#define COUT  64
#define HW    16384           // 128*128
#define NPIX  (32 * HW)       // 524288
#define HALF  (NPIX / 2)      // 262144

// ---------------------------------------------------------------------------
// Prep: pack (w - wzp) into int8 dwords + fold all requant params.
// wp[o*16 + k] = w[o][4k..4k+3]-wzp as 4 signed bytes.
// params[o] = { scale, bias/os + ozp, unused, as_float((128-izp)*sum_w) }
// ---------------------------------------------------------------------------
__global__ void prep_kernel(const int* __restrict__ w,
                            const float* __restrict__ wscale,
                            const int* __restrict__ wzp,
                            const float* __restrict__ bias,
                            const float* __restrict__ is_p,
                            const int* __restrict__ izp_p,
                            const float* __restrict__ os_p,
                            const int* __restrict__ ozp_p,
                            int* __restrict__ wp,
                            float4* __restrict__ params) {
    int o = threadIdx.x;
    if (o >= COUT) return;
    int zp = wzp[o];
    int sum = 0;
    #pragma unroll
    for (int k = 0; k < 16; ++k) {
        int c0 = w[o * CIN + 4 * k + 0] - zp;
        int c1 = w[o * CIN + 4 * k + 1] - zp;
        int c2 = w[o * CIN + 4 * k + 2] - zp;
        int c3 = w[o * CIN + 4 * k + 3] - zp;
        sum += c0 + c1 + c2 + c3;
        wp[o * 16 + k] = (c0 & 0xff) | ((c1 & 0xff) << 8) |
                         ((c2 & 0xff) << 16) | ((c3 & 0xff) << 24);
    }
    float4 pr;
    pr.x = is_p[0] * wscale[o] / os_p[0];
    pr.y = bias[o] / os_p[0] + (float)ozp_p[0];
    pr.z = 0.0f;
    pr.w = __int_as_float((128 - izp_p[0]) * sum);  // izp correction, exact
    params[o] = pr;
}

__device__ __forceinline__ int pack4(int v0, int v1, int v2, int v3) {
    // x in [0,255]; (x-128) as int8 == low byte XOR 0x80
    return (v0 | (v1 << 8) | (v2 << 16) | (v3 << 24)) ^ 0x80808080;
}

// ---------------------------------------------------------------------------
// One pixel's 64 outputs; if PREF, interleave the NEXT pixel's 64 channel
// loads (rotating 4-chunk buffer, consumed 4 chunks after issue) so global
// loads stay in flight under the sdot4 stream instead of bursting.
// ---------------------------------------------------------------------------
template <bool PREF>
__device__ __forceinline__ void pixel_pass(const int* __restrict__ s_wp,
                                           const float4* __restrict__ s_par,
                                           const int px[16], int nx[16],
                                           const int* __restrict__ xn,
                                           int* __restrict__ ob) {
    int buf[4][4];
    if constexpr (PREF) {
        #pragma unroll
        for (int d = 0; d < 4; ++d) {
            buf[d][0] = xn[(4 * d + 0) * HW];
            buf[d][1] = xn[(4 * d + 1) * HW];
            buf[d][2] = xn[(4 * d + 2) * HW];
            buf[d][3] = xn[(4 * d + 3) * HW];
        }
    }
    #pragma unroll
    for (int c = 0; c < 16; ++c) {
        #pragma unroll
        for (int oo = 0; oo < 4; ++oo) {
            int o = c * 4 + oo;
            const int4* wv = (const int4*)(s_wp + o * 16);
            int4 w0 = wv[0], w1 = wv[1], w2 = wv[2], w3 = wv[3];
            float4 pr = s_par[o];
            int acc = __float_as_int(pr.w);     // (128-izp)*sum_w, 0 here

            acc = __builtin_amdgcn_sdot4(px[0],  w0.x, acc, false);
            acc = __builtin_amdgcn_sdot4(px[1],  w0.y, acc, false);
            acc = __builtin_amdgcn_sdot4(px[2],  w0.z, acc, false);
            acc = __builtin_amdgcn_sdot4(px[3],  w0.w, acc, false);
            acc = __builtin_amdgcn_sdot4(px[4],  w1.x, acc, false);
            acc = __builtin_amdgcn_sdot4(px[5],  w1.y, acc, false);
            acc = __builtin_amdgcn_sdot4(px[6],  w1.z, acc, false);
            acc = __builtin_amdgcn_sdot4(px[7],  w1.w, acc, false);
            acc = __builtin_amdgcn_sdot4(px[8],  w2.x, acc, false);
            acc = __builtin_amdgcn_sdot4(px[9],  w2.y, acc, false);
            acc = __builtin_amdgcn_sdot4(px[10], w2.z, acc, false);
            acc = __builtin_amdgcn_sdot4(px[11], w2.w, acc, false);
            acc = __builtin_amdgcn_sdot4(px[12], w3.x, acc, false);
            acc = __builtin_amdgcn_sdot4(px[13], w3.y, acc, false);
            acc = __builtin_amdgcn_sdot4(px[14], w3.z, acc, false);
            acc = __builtin_amdgcn_sdot4(px[15], w3.w, acc, false);

            float f = fmaf((float)acc, pr.x, pr.y);
            f = rintf(f);                        // round-half-even == jnp.round
            f = fminf(fmaxf(f, 0.0f), 255.0f);
            __builtin_nontemporal_store((int)f, ob + o * HW);
        }
        if constexpr (PREF) {
            // consume the chunk issued 4 chunks ago, then refill the slot
            nx[c] = pack4(buf[c & 3][0], buf[c & 3][1], buf[c & 3][2], buf[c & 3][3]);
            if (c < 12) {
                int cg = c + 4;
                buf[c & 3][0] = xn[(4 * cg + 0) * HW];
                buf[c & 3][1] = xn[(4 * cg + 1) * HW];
                buf[c & 3][2] = xn[(4 * cg + 2) * HW];
                buf[c & 3][3] = xn[(4 * cg + 3) * HW];
            }
        }
    }
}

// ---------------------------------------------------------------------------
// Main: 2 pixels/thread (t and t+HALF), software-pipelined. 1024 blocks x 256.
// ---------------------------------------------------------------------------
__global__ __launch_bounds__(256) void conv_kernel(
    const int* __restrict__ x,
    const int* __restrict__ wp_g,
    const float4* __restrict__ params_g,
    int* __restrict__ out) {

    __shared__ int    s_wp[COUT * 16];   // 4 KB packed weights
    __shared__ float4 s_par[COUT];       // 1 KB params

    int tid = threadIdx.x;
    ((int4*)s_wp)[tid] = ((const int4*)wp_g)[tid];
    if (tid < COUT) s_par[tid] = params_g[tid];
    __syncthreads();

    int t  = blockIdx.x * 256 + tid;     // pixel A
    int tB = t + HALF;                   // pixel B
    int bA = t  >> 14, pA = t  & (HW - 1);
    int bB = tB >> 14, pB = tB & (HW - 1);

    const int* xA = x + bA * (CIN * HW) + pA;
    const int* xB = x + bB * (CIN * HW) + pB;
    int* obA = out + bA * (COUT * HW) + pA;
    int* obB = out + bB * (COUT * HW) + pB;

    // prologue: load+pack pixel A
    int px[16], nx[16];
    #pragma unroll
    for (int cg = 0; cg < 16; ++cg)
        px[cg] = pack4(xA[(4 * cg + 0) * HW], xA[(4 * cg + 1) * HW],
                       xA[(4 * cg + 2) * HW], xA[(4 * cg + 3) * HW]);

    pixel_pass<true >(s_wp, s_par, px, nx, xB, obA);  // compute A, prefetch B
    pixel_pass<false>(s_wp, s_par, nx, px, xB, obB);  // compute B
}

extern "C" void kernel_launch(void* const* d_in, const int* in_sizes, int n_in,
                              void* d_out, int out_size, void* d_ws, size_t ws_size,
                              hipStream_t stream) {
    const int*   x      = (const int*)d_in[0];     // [32,64,128,128] int32
    const float* is_p   = (const float*)d_in[1];
    const int*   izp_p  = (const int*)d_in[2];
    const int*   w      = (const int*)d_in[3];     // [64,64,1,1] int32
    const float* wscale = (const float*)d_in[4];
    const int*   wzp    = (const int*)d_in[5];
    const float* bias   = (const float*)d_in[6];
    const float* os_p   = (const float*)d_in[7];
    const int*   ozp_p  = (const int*)d_in[8];

    int* out = (int*)d_out;

    int*    wp     = (int*)d_ws;                       // 4096 B
    float4* params = (float4*)((char*)d_ws + 4096);    // 1024 B

    prep_kernel<<<1, 64, 0, stream>>>(w, wscale, wzp, bias, is_p, izp_p, os_p,
                                      ozp_p, wp, params);

    // 524288 pixels / 2 per thread / 256 per block = 1024 blocks
    conv_kernel<<<1024, 256, 0, stream>>>(x, wp, params, out);
}

// Round 5
// 276.822 us; speedup vs baseline: 1.0310x; 1.0310x over previous
//
#include <hip/hip_runtime.h>

// Problem constants: B=32, CIN=64, COUT=64, H=W=128, 1x1 conv
#define CIN   64
#define COUT  64
#define HW    16384           // 128*128
#define NPIX  (32 * HW)       // 524288

#define BLOCKS 512
#define SPAN   1024           // pixels per block (within one image: 16384 % 1024 == 0)
#define GRP    128            // pixels per staged group
#define NGRP   (SPAN / GRP)   // 8

// ---------------------------------------------------------------------------
// Prep: pack (w - wzp) into int8 dwords + fold requant params.
// wp[o*16 + k] = w[o][4k..4k+3]-wzp as 4 signed bytes (c0 in low byte).
// params[o] = { scale, bias/os + ozp, 0, as_float((128-izp)*sum_w) }
// ---------------------------------------------------------------------------
__global__ void prep_kernel(const int* __restrict__ w,
                            const float* __restrict__ wscale,
                            const int* __restrict__ wzp,
                            const float* __restrict__ bias,
                            const float* __restrict__ is_p,
                            const int* __restrict__ izp_p,
                            const float* __restrict__ os_p,
                            const int* __restrict__ ozp_p,
                            int* __restrict__ wp,
                            float4* __restrict__ params) {
    int o = threadIdx.x;
    if (o >= COUT) return;
    int zp = wzp[o];
    int sum = 0;
    #pragma unroll
    for (int k = 0; k < 16; ++k) {
        int c0 = w[o * CIN + 4 * k + 0] - zp;
        int c1 = w[o * CIN + 4 * k + 1] - zp;
        int c2 = w[o * CIN + 4 * k + 2] - zp;
        int c3 = w[o * CIN + 4 * k + 3] - zp;
        sum += c0 + c1 + c2 + c3;
        wp[o * 16 + k] = (c0 & 0xff) | ((c1 & 0xff) << 8) |
                         ((c2 & 0xff) << 16) | ((c3 & 0xff) << 24);
    }
    float4 pr;
    pr.x = is_p[0] * wscale[o] / os_p[0];
    pr.y = bias[o] / os_p[0] + (float)ozp_p[0];
    pr.z = 0.0f;
    pr.w = __int_as_float((128 - izp_p[0]) * sum);  // exact izp correction
    params[o] = pr;
}

// ---------------------------------------------------------------------------
// Streaming kernel: block owns 1024 px, 8 groups of 128 px, double-buffered
// LDS staging via global_load_lds (async DMA, zero VGPR cost). While group g
// is computed from LDS, group g+1 streams from HBM -> continuous read+write
// overlap per CU (fixes R3's phase lockstep).
//   thread t: pixel px = t&127, output half oh = t>>7 (32 outputs each).
//   LDS tile layout: [c][px] int32 (matches DMA lane order: lane*16B).
//   Weights/params: readfirstlane-forced scalar loads (s_load, K$-resident).
// ---------------------------------------------------------------------------
__global__ __launch_bounds__(256) void conv_kernel(
    const int* __restrict__ x,
    const int* __restrict__ wp_g,
    const float4* __restrict__ params_g,
    int* __restrict__ out) {

    __shared__ int s_x[2][CIN * GRP];   // 2 x 32 KB -> 2 blocks/CU

    const int tid  = threadIdx.x;
    const int lane = tid & 63;
    const int wv   = tid >> 6;          // wave id 0..3
    const int px   = tid & (GRP - 1);
    const int oh   = __builtin_amdgcn_readfirstlane(tid >> 7);  // wave-uniform 0/1

    const int pix_base = blockIdx.x * SPAN;
    const int bimg = pix_base >> 14;          // image index
    const int p0   = pix_base & (HW - 1);     // offset within image
    const int* ximg = x   + bimg * (CIN * HW) + p0;
    int*       oimg = out + bimg * (COUT * HW) + p0;

    // DMA one group into buffer nb. Per wave: 8 instrs x (64 lanes x 16 B) =
    // 8 KB; 4 waves cover the 32 KB tile. Lane L of instr j fetches channel
    // c = wv*16 + 2j + (L>>5), pixels 4*(L&31)..+3 -> LDS base + L*16.
    auto issue = [&](int g, int nb) {
        const int* gbase = ximg + g * GRP + ((lane & 31) * 4);
        #pragma unroll
        for (int j = 0; j < 8; ++j) {
            int c = wv * 16 + 2 * j + (lane >> 5);
            const int* gp = gbase + c * HW;
            int* lp = &s_x[nb][(wv * 16 + 2 * j) * GRP];   // wave-uniform base
            __builtin_amdgcn_global_load_lds(
                (const __attribute__((address_space(1))) void*)gp,
                (__attribute__((address_space(3))) void*)lp, 16, 0, 0);
        }
    };

    issue(0, 0);

    for (int g = 0; g < NGRP; ++g) {
        __syncthreads();   // compiler drains vmcnt -> buf[g&1] is ready
        if (g + 1 < NGRP) issue(g + 1, (g + 1) & 1);

        // pack this pixel's 64 channels from LDS: 64 ds_read_b32, px
        // consecutive across lanes -> 2-way bank aliasing (free)
        const int* xp = &s_x[g & 1][px];
        int pk[16];
        #pragma unroll
        for (int cg = 0; cg < 16; ++cg) {
            int v0 = xp[(4 * cg + 0) * GRP];
            int v1 = xp[(4 * cg + 1) * GRP];
            int v2 = xp[(4 * cg + 2) * GRP];
            int v3 = xp[(4 * cg + 3) * GRP];
            // x in [0,255]; (x-128) as int8 == low byte XOR 0x80
            pk[cg] = (v0 | (v1 << 8) | (v2 << 16) | (v3 << 24)) ^ 0x80808080;
        }

        int* og = oimg + g * GRP + px;
        #pragma unroll 4
        for (int i = 0; i < 32; ++i) {
            int o = oh * 32 + i;                       // scalar (oh uniform)
            const int4* wvp = (const int4*)(wp_g + o * 16);
            int4 w0 = wvp[0], w1 = wvp[1], w2 = wvp[2], w3 = wvp[3];
            float4 pr = params_g[o];
            int acc = __float_as_int(pr.w);            // (128-izp)*sum_w

            acc = __builtin_amdgcn_sdot4(pk[0],  w0.x, acc, false);
            acc = __builtin_amdgcn_sdot4(pk[1],  w0.y, acc, false);
            acc = __builtin_amdgcn_sdot4(pk[2],  w0.z, acc, false);
            acc = __builtin_amdgcn_sdot4(pk[3],  w0.w, acc, false);
            acc = __builtin_amdgcn_sdot4(pk[4],  w1.x, acc, false);
            acc = __builtin_amdgcn_sdot4(pk[5],  w1.y, acc, false);
            acc = __builtin_amdgcn_sdot4(pk[6],  w1.z, acc, false);
            acc = __builtin_amdgcn_sdot4(pk[7],  w1.w, acc, false);
            acc = __builtin_amdgcn_sdot4(pk[8],  w2.x, acc, false);
            acc = __builtin_amdgcn_sdot4(pk[9],  w2.y, acc, false);
            acc = __builtin_amdgcn_sdot4(pk[10], w2.z, acc, false);
            acc = __builtin_amdgcn_sdot4(pk[11], w2.w, acc, false);
            acc = __builtin_amdgcn_sdot4(pk[12], w3.x, acc, false);
            acc = __builtin_amdgcn_sdot4(pk[13], w3.y, acc, false);
            acc = __builtin_amdgcn_sdot4(pk[14], w3.z, acc, false);
            acc = __builtin_amdgcn_sdot4(pk[15], w3.w, acc, false);

            float f = fmaf((float)acc, pr.x, pr.y);
            f = rintf(f);                              // round-half-even == jnp.round
            f = fminf(fmaxf(f, 0.0f), 255.0f);
            __builtin_nontemporal_store((int)f, og + o * HW);
        }
    }
}

extern "C" void kernel_launch(void* const* d_in, const int* in_sizes, int n_in,
                              void* d_out, int out_size, void* d_ws, size_t ws_size,
                              hipStream_t stream) {
    const int*   x      = (const int*)d_in[0];     // [32,64,128,128] int32
    const float* is_p   = (const float*)d_in[1];
    const int*   izp_p  = (const int*)d_in[2];
    const int*   w      = (const int*)d_in[3];     // [64,64,1,1] int32
    const float* wscale = (const float*)d_in[4];
    const int*   wzp    = (const int*)d_in[5];
    const float* bias   = (const float*)d_in[6];
    const float* os_p   = (const float*)d_in[7];
    const int*   ozp_p  = (const int*)d_in[8];

    int* out = (int*)d_out;

    int*    wp     = (int*)d_ws;                       // 4096 B
    float4* params = (float4*)((char*)d_ws + 4096);    // 1024 B

    prep_kernel<<<1, 64, 0, stream>>>(w, wscale, wzp, bias, is_p, izp_p, os_p,
                                      ozp_p, wp, params);

    conv_kernel<<<BLOCKS, 256, 0, stream>>>(x, wp, params, out);
}

// Round 6
// 258.143 us; speedup vs baseline: 1.1056x; 1.0724x over previous
//
#include <hip/hip_runtime.h>

// Problem constants: B=32, CIN=64, COUT=64, H=W=128, 1x1 conv
#define CIN   64
#define COUT  64
#define HW    16384           // 128*128
#define NPIX  (32 * HW)       // 524288
#define HALF  (NPIX / 2)      // 262144

// ---------------------------------------------------------------------------
// Prep: pack (w - wzp) into int8 dwords + fold requant params.
// wp[o*16 + k] = w[o][4k..4k+3]-wzp as 4 signed bytes (c0 in low byte).
// params[o] = { scale, bias/os + ozp, 0, as_float((128-izp)*sum_w) }
// ---------------------------------------------------------------------------
__global__ void prep_kernel(const int* __restrict__ w,
                            const float* __restrict__ wscale,
                            const int* __restrict__ wzp,
                            const float* __restrict__ bias,
                            const float* __restrict__ is_p,
                            const int* __restrict__ izp_p,
                            const float* __restrict__ os_p,
                            const int* __restrict__ ozp_p,
                            int* __restrict__ wp,
                            float4* __restrict__ params) {
    int o = threadIdx.x;
    if (o >= COUT) return;
    int zp = wzp[o];
    int sum = 0;
    #pragma unroll
    for (int k = 0; k < 16; ++k) {
        int c0 = w[o * CIN + 4 * k + 0] - zp;
        int c1 = w[o * CIN + 4 * k + 1] - zp;
        int c2 = w[o * CIN + 4 * k + 2] - zp;
        int c3 = w[o * CIN + 4 * k + 3] - zp;
        sum += c0 + c1 + c2 + c3;
        wp[o * 16 + k] = (c0 & 0xff) | ((c1 & 0xff) << 8) |
                         ((c2 & 0xff) << 16) | ((c3 & 0xff) << 24);
    }
    float4 pr;
    pr.x = is_p[0] * wscale[o] / os_p[0];
    pr.y = bias[o] / os_p[0] + (float)ozp_p[0];
    pr.z = 0.0f;
    pr.w = __int_as_float((128 - izp_p[0]) * sum);  // exact izp correction
    params[o] = pr;
}

__device__ __forceinline__ int pack4(int v0, int v1, int v2, int v3) {
    // x in [0,255]; (x-128) as int8 == low byte XOR 0x80
    return (v0 | (v1 << 8) | (v2 << 16) | (v3 << 24)) ^ 0x80808080;
}

// ---------------------------------------------------------------------------
// Main: 2048 blocks x 128 threads, 2 sequential pixels per thread
// (t and t+HALF). 16 blocks/CU x 2 waves = 32 waves/CU (full TLP) AND two
// load->compute->store cycles per wave (de-phases read/write streams after
// cycle 1; px-B loads overlap px-A store drain). No LDS, no barriers —
// weights/params come from wave-uniform global loads (s_load, scalar K$,
// zero VGPR cost; sdot4 takes one SGPR operand fine).
// ---------------------------------------------------------------------------
__global__ __launch_bounds__(128) void conv_kernel(
    const int* __restrict__ x,
    const int* __restrict__ wp_g,
    const float4* __restrict__ params_g,
    int* __restrict__ out) {

    const int tid = threadIdx.x;
    const int t0  = blockIdx.x * 128 + tid;    // 0..262143

    #pragma unroll
    for (int half = 0; half < 2; ++half) {
        int t = t0 + half * HALF;
        int b = t >> 14;                       // image
        int p = t & (HW - 1);                  // pixel within image

        const int* xb = x + b * (CIN * HW) + p;

        // load + pack this pixel's 64 channels (64 coalesced dword loads)
        int pk[16];
        #pragma unroll
        for (int cg = 0; cg < 16; ++cg) {
            int v0 = xb[(4 * cg + 0) * HW];
            int v1 = xb[(4 * cg + 1) * HW];
            int v2 = xb[(4 * cg + 2) * HW];
            int v3 = xb[(4 * cg + 3) * HW];
            pk[cg] = pack4(v0, v1, v2, v3);
        }

        int* ob = out + b * (COUT * HW) + p;

        #pragma unroll 8
        for (int o = 0; o < COUT; ++o) {
            // o is uniform -> these become s_load (SGPR weights, K$-resident)
            const int4* wv = (const int4*)(wp_g + o * 16);
            int4 w0 = wv[0], w1 = wv[1], w2 = wv[2], w3 = wv[3];
            float4 pr = params_g[o];
            int acc = __float_as_int(pr.w);    // (128-izp)*sum_w (0 here)

            acc = __builtin_amdgcn_sdot4(pk[0],  w0.x, acc, false);
            acc = __builtin_amdgcn_sdot4(pk[1],  w0.y, acc, false);
            acc = __builtin_amdgcn_sdot4(pk[2],  w0.z, acc, false);
            acc = __builtin_amdgcn_sdot4(pk[3],  w0.w, acc, false);
            acc = __builtin_amdgcn_sdot4(pk[4],  w1.x, acc, false);
            acc = __builtin_amdgcn_sdot4(pk[5],  w1.y, acc, false);
            acc = __builtin_amdgcn_sdot4(pk[6],  w1.z, acc, false);
            acc = __builtin_amdgcn_sdot4(pk[7],  w1.w, acc, false);
            acc = __builtin_amdgcn_sdot4(pk[8],  w2.x, acc, false);
            acc = __builtin_amdgcn_sdot4(pk[9],  w2.y, acc, false);
            acc = __builtin_amdgcn_sdot4(pk[10], w2.z, acc, false);
            acc = __builtin_amdgcn_sdot4(pk[11], w2.w, acc, false);
            acc = __builtin_amdgcn_sdot4(pk[12], w3.x, acc, false);
            acc = __builtin_amdgcn_sdot4(pk[13], w3.y, acc, false);
            acc = __builtin_amdgcn_sdot4(pk[14], w3.z, acc, false);
            acc = __builtin_amdgcn_sdot4(pk[15], w3.w, acc, false);

            float f = fmaf((float)acc, pr.x, pr.y);
            f = rintf(f);                        // round-half-even == jnp.round
            f = fminf(fmaxf(f, 0.0f), 255.0f);
            __builtin_nontemporal_store((int)f, ob + o * HW);
        }
    }
}

extern "C" void kernel_launch(void* const* d_in, const int* in_sizes, int n_in,
                              void* d_out, int out_size, void* d_ws, size_t ws_size,
                              hipStream_t stream) {
    const int*   x      = (const int*)d_in[0];     // [32,64,128,128] int32
    const float* is_p   = (const float*)d_in[1];
    const int*   izp_p  = (const int*)d_in[2];
    const int*   w      = (const int*)d_in[3];     // [64,64,1,1] int32
    const float* wscale = (const float*)d_in[4];
    const int*   wzp    = (const int*)d_in[5];
    const float* bias   = (const float*)d_in[6];
    const float* os_p   = (const float*)d_in[7];
    const int*   ozp_p  = (const int*)d_in[8];

    int* out = (int*)d_out;

    int*    wp     = (int*)d_ws;                       // 4096 B
    float4* params = (float4*)((char*)d_ws + 4096);    // 1024 B

    prep_kernel<<<1, 64, 0, stream>>>(w, wscale, wzp, bias, is_p, izp_p, os_p,
                                      ozp_p, wp, params);

    // 262144 threads x 2 px = 524288 pixels; 2048 blocks x 128 threads
    conv_kernel<<<2048, 128, 0, stream>>>(x, wp, params, out);
}